// Round 1
// baseline (773.955 us; speedup 1.0000x reference)
//
#include <hip/hip_runtime.h>

#define N_NODES 50000
#define N_EDGES 800000
#define D 128
#define NLAYER 4
#define NGRAPH 128
#define GDIM (5 * D) // 640

// ---------------- CSR build ----------------

__global__ void k_count(const int* __restrict__ edst, int* __restrict__ cnt) {
    int e = blockIdx.x * 256 + threadIdx.x;
    if (e < N_EDGES) atomicAdd(&cnt[edst[e]], 1);
}

__global__ void k_dinv(const int* __restrict__ cnt, float* __restrict__ dinv) {
    int i = blockIdx.x * 256 + threadIdx.x;
    if (i < N_NODES) dinv[i] = 1.f / sqrtf((float)(cnt[i] + 1)); // +1 self-loop
}

// 2-level exclusive scan, chunk = 1024 elements (256 thr x 4)
__global__ void k_scanA(const int* __restrict__ cnt, int* __restrict__ offs,
                        int* __restrict__ chunkSum) {
    __shared__ int lds[256];
    int tid = threadIdx.x;
    int base = blockIdx.x * 1024 + tid * 4;
    int v[4];
    int s = 0;
#pragma unroll
    for (int j = 0; j < 4; ++j) {
        int idx = base + j;
        v[j] = (idx < N_NODES) ? cnt[idx] : 0;
        s += v[j];
    }
    lds[tid] = s;
    __syncthreads();
    int t = s;
    for (int off = 1; off < 256; off <<= 1) {
        int add = (tid >= off) ? lds[tid - off] : 0;
        __syncthreads();
        t += add;
        lds[tid] = t;
        __syncthreads();
    }
    int run = t - s; // exclusive prefix for this thread within chunk
#pragma unroll
    for (int j = 0; j < 4; ++j) {
        int idx = base + j;
        if (idx < N_NODES) offs[idx] = run;
        run += v[j];
    }
    if (tid == 255) chunkSum[blockIdx.x] = t;
}

__global__ void k_scanB(const int* __restrict__ chunkSum, int* __restrict__ chunkOff,
                        int nc) {
    __shared__ int lds[64];
    int tid = threadIdx.x;
    int v = (tid < nc) ? chunkSum[tid] : 0;
    lds[tid] = v;
    __syncthreads();
    int t = v;
    for (int off = 1; off < 64; off <<= 1) {
        int add = (tid >= off) ? lds[tid - off] : 0;
        __syncthreads();
        t += add;
        lds[tid] = t;
        __syncthreads();
    }
    if (tid < nc) chunkOff[tid] = t - v;
}

__global__ void k_scanC(int* __restrict__ offs, const int* __restrict__ chunkOff) {
    int i = blockIdx.x * 256 + threadIdx.x;
    if (i < N_NODES) offs[i] += chunkOff[i >> 10];
}

__global__ void k_fill(const int* __restrict__ esrc, const int* __restrict__ edst,
                       const float* __restrict__ dinv, const int* __restrict__ offs,
                       int* __restrict__ fillp, int2* __restrict__ csr) {
    int e = blockIdx.x * 256 + threadIdx.x;
    if (e >= N_EDGES) return;
    int s = esrc[e], d = edst[e];
    int p = atomicAdd(&fillp[d], 1);
    float w = dinv[s] * dinv[d];
    csr[offs[d] + p] = make_int2(s, __float_as_int(w));
}

// ---------------- node encoder: x = relu(cat(relu(pos@Wp+bp), relu(emb[id])) @ Wn + bn)

__global__ __launch_bounds__(256) void k_encoder(
    const float* __restrict__ pos, const int* __restrict__ idfeat,
    const float* __restrict__ Wp, const float* __restrict__ bp,
    const float* __restrict__ id_emb, const float* __restrict__ Wn,
    const float* __restrict__ bn, float* __restrict__ A) {
    __shared__ float feat[32][256];
    int t = threadIdx.x;
    int base = blockIdx.x * 32;
    for (int r = 0; r < 32; ++r) {
        int node = base + r;
        float v = 0.f;
        if (node < N_NODES) {
            if (t < 128) {
                float p0 = pos[node * 3 + 0], p1 = pos[node * 3 + 1], p2 = pos[node * 3 + 2];
                v = fmaxf(fmaf(p0, Wp[t], fmaf(p1, Wp[128 + t], fmaf(p2, Wp[256 + t], bp[t]))), 0.f);
            } else {
                int id = idfeat[node];
                v = fmaxf(id_emb[id * 128 + (t - 128)], 0.f);
            }
        }
        feat[r][t] = v;
    }
    __syncthreads();
    int d = t & 127, half = t >> 7;
    float acc[16];
    float b = bn[d];
#pragma unroll
    for (int i = 0; i < 16; ++i) acc[i] = b;
    for (int k4 = 0; k4 < 64; ++k4) {
        int k = k4 * 4;
        float w0 = Wn[(k + 0) * 128 + d];
        float w1 = Wn[(k + 1) * 128 + d];
        float w2 = Wn[(k + 2) * 128 + d];
        float w3 = Wn[(k + 3) * 128 + d];
#pragma unroll
        for (int rr = 0; rr < 16; ++rr) {
            float4 f = *(const float4*)&feat[half * 16 + rr][k];
            acc[rr] = fmaf(f.x, w0, acc[rr]);
            acc[rr] = fmaf(f.y, w1, acc[rr]);
            acc[rr] = fmaf(f.z, w2, acc[rr]);
            acc[rr] = fmaf(f.w, w3, acc[rr]);
        }
    }
    for (int rr = 0; rr < 16; ++rr) {
        int node = base + half * 16 + rr;
        if (node < N_NODES) A[(size_t)node * 128 + d] = fmaxf(acc[rr], 0.f);
    }
}

// ---------------- dense GEMM: out[N,128] = H[N,128] @ W[128,128] (no bias/relu)

__global__ __launch_bounds__(256) void k_gemm(
    const float* __restrict__ H, const float* __restrict__ W, float* __restrict__ out) {
    __shared__ float feat[32][128];
    int t = threadIdx.x;
    int base = blockIdx.x * 32;
    {
        const float4* src = (const float4*)(H + (size_t)base * 128);
        float4* dstl = (float4*)&feat[0][0];
        int avail = N_NODES - base;
        if (avail >= 32) {
            for (int i = t; i < 1024; i += 256) dstl[i] = src[i];
        } else {
            for (int i = t; i < 1024; i += 256) {
                int row = i >> 5;
                float4 v = make_float4(0.f, 0.f, 0.f, 0.f);
                if (row < avail) v = src[i];
                dstl[i] = v;
            }
        }
    }
    __syncthreads();
    int d = t & 127, half = t >> 7;
    float acc[16];
#pragma unroll
    for (int i = 0; i < 16; ++i) acc[i] = 0.f;
    for (int k4 = 0; k4 < 32; ++k4) {
        int k = k4 * 4;
        float w0 = W[(k + 0) * 128 + d];
        float w1 = W[(k + 1) * 128 + d];
        float w2 = W[(k + 2) * 128 + d];
        float w3 = W[(k + 3) * 128 + d];
#pragma unroll
        for (int rr = 0; rr < 16; ++rr) {
            float4 f = *(const float4*)&feat[half * 16 + rr][k];
            acc[rr] = fmaf(f.x, w0, acc[rr]);
            acc[rr] = fmaf(f.y, w1, acc[rr]);
            acc[rr] = fmaf(f.z, w2, acc[rr]);
            acc[rr] = fmaf(f.w, w3, acc[rr]);
        }
    }
    for (int rr = 0; rr < 16; ++rr) {
        int node = base + half * 16 + rr;
        if (node < N_NODES) out[(size_t)node * 128 + d] = acc[rr];
    }
}

// ---------------- GCN aggregate: A[i] = relu(sum_e w_e * B[src_e] + dinv_i^2 * B[i] + bias)

__global__ __launch_bounds__(256) void k_gather(
    const float* __restrict__ B, float* __restrict__ A,
    const int* __restrict__ offs, const int* __restrict__ cnt,
    const int2* __restrict__ csr, const float* __restrict__ dinv,
    const float* __restrict__ bias) {
    int node = blockIdx.x * 4 + (threadIdx.x >> 6);
    if (node >= N_NODES) return;
    int lane = threadIdx.x & 63;
    int start = offs[node];
    int c = cnt[node];
    float di = dinv[node];
    float sw = di * di;
    float2 self = ((const float2*)(B + (size_t)node * 128))[lane];
    float2 acc;
    acc.x = sw * self.x;
    acc.y = sw * self.y;
    for (int j = 0; j < c; ++j) {
        int2 e = csr[start + j];
        float w = __int_as_float(e.y);
        float2 v = ((const float2*)(B + (size_t)e.x * 128))[lane];
        acc.x = fmaf(w, v.x, acc.x);
        acc.y = fmaf(w, v.y, acc.y);
    }
    float2 bb = ((const float2*)bias)[lane];
    acc.x = fmaxf(acc.x + bb.x, 0.f);
    acc.y = fmaxf(acc.y + bb.y, 0.f);
    ((float2*)(A + (size_t)node * 128))[lane] = acc;
}

// ---------------- segment max (batch is sorted; 8 nodes/thread, then one atomic)

__global__ void k_segmax(const float* __restrict__ A, float* __restrict__ gbuf,
                         const int* __restrict__ batch, int off) {
    int gid = blockIdx.x * blockDim.x + threadIdx.x;
    int d = gid & 127;
    int chunk = gid >> 7;
    int n0 = chunk * 8;
    if (n0 >= N_NODES) return;
    float m = 0.f;
    int curg = -1;
    for (int i = 0; i < 8; ++i) {
        int node = n0 + i;
        if (node >= N_NODES) break;
        int g = batch[node];
        if (g != curg) {
            if (curg >= 0) atomicMax((int*)&gbuf[curg * GDIM + off + d], __float_as_int(m));
            curg = g;
            m = 0.f;
        }
        m = fmaxf(m, A[(size_t)node * 128 + d]);
    }
    if (curg >= 0) atomicMax((int*)&gbuf[curg * GDIM + off + d], __float_as_int(m));
}

// ---------------- final: out[G,128] = gbuf[G,640] @ Wa[640,128] + ba

__global__ __launch_bounds__(128) void k_final(const float* __restrict__ gbuf,
                                               const float* __restrict__ Wa,
                                               const float* __restrict__ ba,
                                               float* __restrict__ out) {
    __shared__ float gr[GDIM];
    int g = blockIdx.x, t = threadIdx.x;
    for (int i = t; i < GDIM; i += 128) gr[i] = gbuf[g * GDIM + i];
    __syncthreads();
    float acc = ba[t];
    for (int k = 0; k < GDIM; ++k) acc = fmaf(gr[k], Wa[k * 128 + t], acc);
    out[g * 128 + t] = acc;
}

// ---------------- launch ----------------

extern "C" void kernel_launch(void* const* d_in, const int* in_sizes, int n_in,
                              void* d_out, int out_size, void* d_ws, size_t ws_size,
                              hipStream_t stream) {
    const float* pos    = (const float*)d_in[0];
    const int*   idfeat = (const int*)d_in[1];
    const int*   eidx   = (const int*)d_in[2];
    const int*   batch  = (const int*)d_in[3];
    const float* Wp     = (const float*)d_in[5];
    const float* bp     = (const float*)d_in[6];
    const float* id_emb = (const float*)d_in[7];
    const float* Wn     = (const float*)d_in[8];
    const float* bn     = (const float*)d_in[9];
    const float* convW  = (const float*)d_in[10];
    const float* convb  = (const float*)d_in[11];
    const float* Wa     = (const float*)d_in[12];
    const float* ba     = (const float*)d_in[13];
    float* out = (float*)d_out;

    const int* esrc = eidx;
    const int* edst = eidx + N_EDGES;

    char* w = (char*)d_ws;
    auto alloc = [&](size_t bytes) -> char* {
        char* p = w;
        w += (bytes + 255) & ~(size_t)255;
        return p;
    };
    float* A    = (float*)alloc((size_t)N_NODES * D * 4);
    float* B    = (float*)alloc((size_t)N_NODES * D * 4);
    float* dinv = (float*)alloc((size_t)N_NODES * 4);
    int*   cnt  = (int*)alloc((size_t)N_NODES * 4);
    int*   offs = (int*)alloc((size_t)(N_NODES + 1) * 4);
    int*   fillp= (int*)alloc((size_t)N_NODES * 4);
    int*   csum = (int*)alloc(64 * 4);
    int*   coff = (int*)alloc(64 * 4);
    int2*  csr  = (int2*)alloc((size_t)N_EDGES * 8);
    float* gbuf = (float*)alloc((size_t)NGRAPH * GDIM * 4);

    hipMemsetAsync(cnt, 0, (size_t)N_NODES * 4, stream);
    hipMemsetAsync(fillp, 0, (size_t)N_NODES * 4, stream);
    hipMemsetAsync(gbuf, 0, (size_t)NGRAPH * GDIM * 4, stream);

    k_count<<<(N_EDGES + 255) / 256, 256, 0, stream>>>(edst, cnt);
    k_dinv<<<(N_NODES + 255) / 256, 256, 0, stream>>>(cnt, dinv);

    int nchunk = (N_NODES + 1023) / 1024; // 49
    k_scanA<<<nchunk, 256, 0, stream>>>(cnt, offs, csum);
    k_scanB<<<1, 64, 0, stream>>>(csum, coff, nchunk);
    k_scanC<<<(N_NODES + 255) / 256, 256, 0, stream>>>(offs, coff);
    k_fill<<<(N_EDGES + 255) / 256, 256, 0, stream>>>(esrc, edst, dinv, offs, fillp, csr);

    k_encoder<<<(N_NODES + 31) / 32, 256, 0, stream>>>(pos, idfeat, Wp, bp, id_emb, Wn, bn, A);

    int segmax_blocks = (((N_NODES + 7) / 8) * 128 + 255) / 256;
    k_segmax<<<segmax_blocks, 256, 0, stream>>>(A, gbuf, batch, 0);

    for (int l = 0; l < NLAYER; ++l) {
        k_gemm<<<(N_NODES + 31) / 32, 256, 0, stream>>>(A, convW + (size_t)l * D * D, B);
        k_gather<<<(N_NODES + 3) / 4, 256, 0, stream>>>(B, A, offs, cnt, csr, dinv, convb + (size_t)l * D);
        k_segmax<<<segmax_blocks, 256, 0, stream>>>(A, gbuf, batch, (l + 1) * D);
    }

    k_final<<<NGRAPH, 128, 0, stream>>>(gbuf, Wa, ba, out);
}

// Round 2
// 590.227 us; speedup vs baseline: 1.3113x; 1.3113x over previous
//
#include <hip/hip_runtime.h>

#define N_NODES 50000
#define N_EDGES 800000
#define D 128
#define NLAYER 4
#define NGRAPH 128
#define GDIM (5 * D) // 640

// ---------------- CSR build ----------------

__global__ void k_count(const int* __restrict__ edst, int* __restrict__ cnt) {
    int e = blockIdx.x * 256 + threadIdx.x;
    if (e < N_EDGES) atomicAdd(&cnt[edst[e]], 1);
}

__global__ void k_dinv(const int* __restrict__ cnt, float* __restrict__ dinv) {
    int i = blockIdx.x * 256 + threadIdx.x;
    if (i < N_NODES) dinv[i] = 1.f / sqrtf((float)(cnt[i] + 1)); // +1 self-loop
}

// 2-level exclusive scan, chunk = 1024 elements (256 thr x 4)
__global__ void k_scanA(const int* __restrict__ cnt, int* __restrict__ offs,
                        int* __restrict__ chunkSum) {
    __shared__ int lds[256];
    int tid = threadIdx.x;
    int base = blockIdx.x * 1024 + tid * 4;
    int v[4];
    int s = 0;
#pragma unroll
    for (int j = 0; j < 4; ++j) {
        int idx = base + j;
        v[j] = (idx < N_NODES) ? cnt[idx] : 0;
        s += v[j];
    }
    lds[tid] = s;
    __syncthreads();
    int t = s;
    for (int off = 1; off < 256; off <<= 1) {
        int add = (tid >= off) ? lds[tid - off] : 0;
        __syncthreads();
        t += add;
        lds[tid] = t;
        __syncthreads();
    }
    int run = t - s;
#pragma unroll
    for (int j = 0; j < 4; ++j) {
        int idx = base + j;
        if (idx < N_NODES) offs[idx] = run;
        run += v[j];
    }
    if (tid == 255) chunkSum[blockIdx.x] = t;
}

__global__ void k_scanB(const int* __restrict__ chunkSum, int* __restrict__ chunkOff,
                        int nc) {
    __shared__ int lds[64];
    int tid = threadIdx.x;
    int v = (tid < nc) ? chunkSum[tid] : 0;
    lds[tid] = v;
    __syncthreads();
    int t = v;
    for (int off = 1; off < 64; off <<= 1) {
        int add = (tid >= off) ? lds[tid - off] : 0;
        __syncthreads();
        t += add;
        lds[tid] = t;
        __syncthreads();
    }
    if (tid < nc) chunkOff[tid] = t - v;
}

__global__ void k_scanC(int* __restrict__ offs, const int* __restrict__ chunkOff) {
    int i = blockIdx.x * 256 + threadIdx.x;
    if (i < N_NODES) offs[i] += chunkOff[i >> 10];
}

__global__ void k_fill(const int* __restrict__ esrc, const int* __restrict__ edst,
                       const float* __restrict__ dinv, const int* __restrict__ offs,
                       int* __restrict__ fillp, int2* __restrict__ csr) {
    int e = blockIdx.x * 256 + threadIdx.x;
    if (e >= N_EDGES) return;
    int s = esrc[e], d = edst[e];
    int p = atomicAdd(&fillp[d], 1);
    float w = dinv[s] * dinv[d];
    csr[offs[d] + p] = make_int2(s, __float_as_int(w));
}

// ---------------- T[256,128] = relu(id_emb) @ Wn_bottom ----------------

__global__ __launch_bounds__(256) void k_idT(const float* __restrict__ id_emb,
                                             const float* __restrict__ Wn,
                                             float* __restrict__ T) {
    int t = threadIdx.x;
    int d = t & 127;
    int r = blockIdx.x * 2 + (t >> 7);
    float acc = 0.f;
    for (int k = 0; k < 128; ++k)
        acc = fmaf(fmaxf(id_emb[r * 128 + k], 0.f), Wn[(128 + k) * 128 + d], acc);
    T[r * 128 + d] = acc;
}

// ---------------- encoder: A = relu(posrelu @ Wn_top + T[id] + bn) ----------------

__global__ __launch_bounds__(256) void k_encoder(
    const float* __restrict__ pos, const int* __restrict__ idfeat,
    const float* __restrict__ Wp, const float* __restrict__ bp,
    const float* __restrict__ Wn, const float* __restrict__ bn,
    const float* __restrict__ T, float* __restrict__ A) {
    __shared__ float feat[64][128];
    __shared__ float posl[192];
    int t = threadIdx.x;
    int base = blockIdx.x * 64;
    if (t < 192) {
        int idx = base * 3 + t;
        posl[t] = (idx < N_NODES * 3) ? pos[idx] : 0.f;
    }
    __syncthreads();
    {
        int d = t & 127, rs = t >> 7;
        float w0 = Wp[d], w1 = Wp[128 + d], w2 = Wp[256 + d], bb = bp[d];
        for (int r = rs; r < 64; r += 2) {
            float v = 0.f;
            if (base + r < N_NODES) {
                float p0 = posl[r * 3], p1 = posl[r * 3 + 1], p2 = posl[r * 3 + 2];
                v = fmaxf(fmaf(p0, w0, fmaf(p1, w1, fmaf(p2, w2, bb))), 0.f);
            }
            feat[r][d] = v;
        }
    }
    __syncthreads();
    int c = (t & 31) * 4;
    int r0 = (t >> 5) * 8;
    float acc[8][4];
#pragma unroll
    for (int i = 0; i < 8; ++i)
#pragma unroll
        for (int j = 0; j < 4; ++j) acc[i][j] = 0.f;
#pragma unroll 2
    for (int k4 = 0; k4 < 32; ++k4) {
        int k = k4 * 4;
        float4 w0 = *(const float4*)&Wn[(k + 0) * 128 + c];
        float4 w1 = *(const float4*)&Wn[(k + 1) * 128 + c];
        float4 w2 = *(const float4*)&Wn[(k + 2) * 128 + c];
        float4 w3 = *(const float4*)&Wn[(k + 3) * 128 + c];
#pragma unroll
        for (int i = 0; i < 8; ++i) {
            float4 f = *(const float4*)&feat[r0 + i][k];
            acc[i][0] = fmaf(f.x, w0.x, fmaf(f.y, w1.x, fmaf(f.z, w2.x, fmaf(f.w, w3.x, acc[i][0]))));
            acc[i][1] = fmaf(f.x, w0.y, fmaf(f.y, w1.y, fmaf(f.z, w2.y, fmaf(f.w, w3.y, acc[i][1]))));
            acc[i][2] = fmaf(f.x, w0.z, fmaf(f.y, w1.z, fmaf(f.z, w2.z, fmaf(f.w, w3.z, acc[i][2]))));
            acc[i][3] = fmaf(f.x, w0.w, fmaf(f.y, w1.w, fmaf(f.z, w2.w, fmaf(f.w, w3.w, acc[i][3]))));
        }
    }
    float4 bb = *(const float4*)&bn[c];
#pragma unroll
    for (int i = 0; i < 8; ++i) {
        int node = base + r0 + i;
        if (node < N_NODES) {
            int id = idfeat[node];
            float4 tv = *(const float4*)&T[id * 128 + c];
            float4 o;
            o.x = fmaxf(acc[i][0] + bb.x + tv.x, 0.f);
            o.y = fmaxf(acc[i][1] + bb.y + tv.y, 0.f);
            o.z = fmaxf(acc[i][2] + bb.z + tv.z, 0.f);
            o.w = fmaxf(acc[i][3] + bb.w + tv.w, 0.f);
            *(float4*)&A[(size_t)node * 128 + c] = o;
        }
    }
}

// ---------------- dense GEMM: out[N,128] = H[N,128] @ W[128,128] ----------------

__global__ __launch_bounds__(256) void k_gemm(
    const float* __restrict__ H, const float* __restrict__ W, float* __restrict__ out) {
    __shared__ float feat[64][128];
    int t = threadIdx.x;
    int base = blockIdx.x * 64;
    {
        const float4* src = (const float4*)(H + (size_t)base * 128);
        float4* dstl = (float4*)&feat[0][0];
        int avail = N_NODES - base;
        if (avail >= 64) {
#pragma unroll
            for (int i = 0; i < 8; ++i) dstl[t + i * 256] = src[t + i * 256];
        } else {
            for (int i = t; i < 2048; i += 256) {
                int row = i >> 5;
                float4 v = make_float4(0.f, 0.f, 0.f, 0.f);
                if (row < avail) v = src[i];
                dstl[i] = v;
            }
        }
    }
    __syncthreads();
    int c = (t & 31) * 4;
    int r0 = (t >> 5) * 8;
    float acc[8][4];
#pragma unroll
    for (int i = 0; i < 8; ++i)
#pragma unroll
        for (int j = 0; j < 4; ++j) acc[i][j] = 0.f;
#pragma unroll 2
    for (int k4 = 0; k4 < 32; ++k4) {
        int k = k4 * 4;
        float4 w0 = *(const float4*)&W[(k + 0) * 128 + c];
        float4 w1 = *(const float4*)&W[(k + 1) * 128 + c];
        float4 w2 = *(const float4*)&W[(k + 2) * 128 + c];
        float4 w3 = *(const float4*)&W[(k + 3) * 128 + c];
#pragma unroll
        for (int i = 0; i < 8; ++i) {
            float4 f = *(const float4*)&feat[r0 + i][k];
            acc[i][0] = fmaf(f.x, w0.x, fmaf(f.y, w1.x, fmaf(f.z, w2.x, fmaf(f.w, w3.x, acc[i][0]))));
            acc[i][1] = fmaf(f.x, w0.y, fmaf(f.y, w1.y, fmaf(f.z, w2.y, fmaf(f.w, w3.y, acc[i][1]))));
            acc[i][2] = fmaf(f.x, w0.z, fmaf(f.y, w1.z, fmaf(f.z, w2.z, fmaf(f.w, w3.z, acc[i][2]))));
            acc[i][3] = fmaf(f.x, w0.w, fmaf(f.y, w1.w, fmaf(f.z, w2.w, fmaf(f.w, w3.w, acc[i][3]))));
        }
    }
#pragma unroll
    for (int i = 0; i < 8; ++i) {
        int node = base + r0 + i;
        if (node < N_NODES) {
            float4 o = make_float4(acc[i][0], acc[i][1], acc[i][2], acc[i][3]);
            *(float4*)&out[(size_t)node * 128 + c] = o;
        }
    }
}

// ---------------- GCN aggregate: A[i] = relu(sum_e w_e*B[src_e] + dinv_i^2*B[i] + bias)

__global__ __launch_bounds__(256) void k_gather(
    const float* __restrict__ B, float* __restrict__ A,
    const int* __restrict__ offs, const int* __restrict__ cnt,
    const int2* __restrict__ csr, const float* __restrict__ dinv,
    const float* __restrict__ bias) {
    int lane = threadIdx.x & 63;
    int sub = lane >> 5;
    int l = lane & 31;
    int node = blockIdx.x * 8 + (threadIdx.x >> 6) * 2 + sub;
    if (node >= N_NODES) return;
    int start = offs[node];
    int c = cnt[node];
    float di = dinv[node];
    float sw = di * di;
    float4 self = ((const float4*)(B + (size_t)node * 128))[l];
    float4 acc;
    acc.x = sw * self.x;
    acc.y = sw * self.y;
    acc.z = sw * self.z;
    acc.w = sw * self.w;
#pragma unroll 2
    for (int j = 0; j < c; ++j) {
        int2 e = csr[start + j];
        float w = __int_as_float(e.y);
        float4 v = ((const float4*)(B + (size_t)e.x * 128))[l];
        acc.x = fmaf(w, v.x, acc.x);
        acc.y = fmaf(w, v.y, acc.y);
        acc.z = fmaf(w, v.z, acc.z);
        acc.w = fmaf(w, v.w, acc.w);
    }
    float4 bb = ((const float4*)bias)[l];
    acc.x = fmaxf(acc.x + bb.x, 0.f);
    acc.y = fmaxf(acc.y + bb.y, 0.f);
    acc.z = fmaxf(acc.z + bb.z, 0.f);
    acc.w = fmaxf(acc.w + bb.w, 0.f);
    ((float4*)(A + (size_t)node * 128))[l] = acc;
}

// ---------------- segment max (batch sorted; 32 nodes/thread, then one atomic)

__global__ void k_segmax(const float* __restrict__ A, float* __restrict__ gbuf,
                         const int* __restrict__ batch, int off) {
    int gid = blockIdx.x * blockDim.x + threadIdx.x;
    int d = gid & 127;
    int chunk = gid >> 7;
    int n0 = chunk * 32;
    if (n0 >= N_NODES) return;
    int nend = n0 + 32;
    if (nend > N_NODES) nend = N_NODES;
    float m = 0.f;
    int curg = batch[n0];
    for (int node = n0; node < nend; ++node) {
        int g = batch[node];
        if (g != curg) {
            atomicMax((int*)&gbuf[curg * GDIM + off + d], __float_as_int(m));
            curg = g;
            m = 0.f;
        }
        m = fmaxf(m, A[(size_t)node * 128 + d]);
    }
    atomicMax((int*)&gbuf[curg * GDIM + off + d], __float_as_int(m));
}

// ---------------- final: out[G,128] = gbuf[G,640] @ Wa[640,128] + ba

__global__ __launch_bounds__(128) void k_final(const float* __restrict__ gbuf,
                                               const float* __restrict__ Wa,
                                               const float* __restrict__ ba,
                                               float* __restrict__ out) {
    __shared__ float gr[GDIM];
    int g = blockIdx.x, t = threadIdx.x;
    for (int i = t; i < GDIM; i += 128) gr[i] = gbuf[g * GDIM + i];
    __syncthreads();
    float acc = ba[t];
    for (int k = 0; k < GDIM; ++k) acc = fmaf(gr[k], Wa[k * 128 + t], acc);
    out[g * 128 + t] = acc;
}

// ---------------- launch ----------------

extern "C" void kernel_launch(void* const* d_in, const int* in_sizes, int n_in,
                              void* d_out, int out_size, void* d_ws, size_t ws_size,
                              hipStream_t stream) {
    const float* pos    = (const float*)d_in[0];
    const int*   idfeat = (const int*)d_in[1];
    const int*   eidx   = (const int*)d_in[2];
    const int*   batch  = (const int*)d_in[3];
    const float* Wp     = (const float*)d_in[5];
    const float* bp     = (const float*)d_in[6];
    const float* id_emb = (const float*)d_in[7];
    const float* Wn     = (const float*)d_in[8];
    const float* bn     = (const float*)d_in[9];
    const float* convW  = (const float*)d_in[10];
    const float* convb  = (const float*)d_in[11];
    const float* Wa     = (const float*)d_in[12];
    const float* ba     = (const float*)d_in[13];
    float* out = (float*)d_out;

    const int* esrc = eidx;
    const int* edst = eidx + N_EDGES;

    char* w = (char*)d_ws;
    auto alloc = [&](size_t bytes) -> char* {
        char* p = w;
        w += (bytes + 255) & ~(size_t)255;
        return p;
    };
    float* A    = (float*)alloc((size_t)N_NODES * D * 4);
    float* B    = (float*)alloc((size_t)N_NODES * D * 4);
    float* dinv = (float*)alloc((size_t)N_NODES * 4);
    int*   cnt  = (int*)alloc((size_t)N_NODES * 4);
    int*   offs = (int*)alloc((size_t)(N_NODES + 1) * 4);
    int*   fillp= (int*)alloc((size_t)N_NODES * 4);
    int*   csum = (int*)alloc(64 * 4);
    int*   coff = (int*)alloc(64 * 4);
    int2*  csr  = (int2*)alloc((size_t)N_EDGES * 8);
    float* gbuf = (float*)alloc((size_t)NGRAPH * GDIM * 4);
    float* T    = (float*)alloc((size_t)256 * D * 4);

    hipMemsetAsync(cnt, 0, (size_t)N_NODES * 4, stream);
    hipMemsetAsync(fillp, 0, (size_t)N_NODES * 4, stream);
    hipMemsetAsync(gbuf, 0, (size_t)NGRAPH * GDIM * 4, stream);

    k_count<<<(N_EDGES + 255) / 256, 256, 0, stream>>>(edst, cnt);
    k_dinv<<<(N_NODES + 255) / 256, 256, 0, stream>>>(cnt, dinv);

    int nchunk = (N_NODES + 1023) / 1024; // 49
    k_scanA<<<nchunk, 256, 0, stream>>>(cnt, offs, csum);
    k_scanB<<<1, 64, 0, stream>>>(csum, coff, nchunk);
    k_scanC<<<(N_NODES + 255) / 256, 256, 0, stream>>>(offs, coff);
    k_fill<<<(N_EDGES + 255) / 256, 256, 0, stream>>>(esrc, edst, dinv, offs, fillp, csr);

    k_idT<<<128, 256, 0, stream>>>(id_emb, Wn, T);
    k_encoder<<<(N_NODES + 63) / 64, 256, 0, stream>>>(pos, idfeat, Wp, bp, Wn, bn, T, A);

    int segmax_blocks = ((((N_NODES + 31) / 32) * 128) + 255) / 256;
    k_segmax<<<segmax_blocks, 256, 0, stream>>>(A, gbuf, batch, 0);

    for (int l = 0; l < NLAYER; ++l) {
        k_gemm<<<(N_NODES + 63) / 64, 256, 0, stream>>>(A, convW + (size_t)l * D * D, B);
        k_gather<<<(N_NODES + 7) / 8, 256, 0, stream>>>(B, A, offs, cnt, csr, dinv, convb + (size_t)l * D);
        k_segmax<<<segmax_blocks, 256, 0, stream>>>(A, gbuf, batch, (l + 1) * D);
    }

    k_final<<<NGRAPH, 128, 0, stream>>>(gbuf, Wa, ba, out);
}